// Round 9
// baseline (594.711 us; speedup 1.0000x reference)
//
#include <hip/hip_runtime.h>
#include <cstdint>

using f32x4 = __attribute__((ext_vector_type(4))) float;
using s16x8 = __attribute__((ext_vector_type(8))) short;
typedef unsigned short u16;

typedef const __attribute__((address_space(1))) uint32_t* gptr_t;
typedef __attribute__((address_space(3))) uint32_t* lptr_t;

__device__ __forceinline__ u16 f2bf(float f) {
  union { float f; uint32_t u; } v; v.f = f;
  uint32_t r = v.u + 0x7FFFu + ((v.u >> 16) & 1u);  // RNE
  return (u16)(r >> 16);
}
__device__ __forceinline__ float bf2f(u16 b) {
  union { uint32_t u; float f; } v; v.u = ((uint32_t)b) << 16;
  return v.f;
}

// ---------------- k0: normalize prompts -> p_bf (bf16, padded to 1024 rows), ws[0,2MB)
__global__ __launch_bounds__(256) void k_prep_prompts(const float* __restrict__ prompts,
                                                      u16* __restrict__ p_bf) {
  const int r = blockIdx.x;
  const int t = threadIdx.x;
  if (r >= 1000) {
    if (t < 128) {
      s16x8 z = {0, 0, 0, 0, 0, 0, 0, 0};
      ((s16x8*)(p_bf + (size_t)r * 1024))[t] = z;
    }
    return;
  }
  float4 x = ((const float4*)(prompts + (size_t)r * 1024))[t];
  float ss = x.x * x.x + x.y * x.y + x.z * x.z + x.w * x.w;
  #pragma unroll
  for (int off = 32; off; off >>= 1) ss += __shfl_xor(ss, off);
  __shared__ float red[4];
  if ((t & 63) == 0) red[t >> 6] = ss;
  __syncthreads();
  float n = fmaxf(sqrtf(red[0] + red[1] + red[2] + red[3]), 1e-12f);
  float inv = 1.0f / n;
  u16* pb = p_bf + (size_t)r * 1024 + t * 4;
  pb[0] = f2bf(x.x * inv); pb[1] = f2bf(x.y * inv);
  pb[2] = f2bf(x.z * inv); pb[3] = f2bf(x.w * inv);
}

// ---------------- k0b: feat fp32 -> bf16 (scratch at start of MIXED region)
__global__ __launch_bounds__(256) void k_feat(const float* __restrict__ feat,
                                              u16* __restrict__ out) {
  const size_t stride = (size_t)gridDim.x * 256;
  const size_t n4 = 67108864ull / 4;
  for (size_t j = (size_t)blockIdx.x * 256 + threadIdx.x; j < n4; j += stride) {
    float4 x = ((const float4*)feat)[j];
    ushort4 o;
    o.x = f2bf(x.x); o.y = f2bf(x.y); o.z = f2bf(x.z); o.w = f2bf(x.w);
    ((ushort4*)out)[j] = o;
  }
}

// ---------------- k1: bf16 MFMA GEMM, double-buffered LDS, ONE barrier per K-step.
// Stage(next tile) issued BEFORE ds_read+MFMA(current) -> staging latency hidden.
// __syncthreads()'s implicit vmcnt(0)/lgkmcnt(0) drain is the correctness fence.
__global__ __launch_bounds__(256) void k_sims(const u16* __restrict__ A,   // [65536][1024] bf16
                                              const u16* __restrict__ B,   // [1024][1024] bf16
                                              u16* __restrict__ C) {       // [65536][1000] bf16
  __shared__ u16 As[2][128 * 32];
  __shared__ u16 Bs[2][128 * 32];
  const int bid = blockIdx.x;                       // grid 4096 = 8 * 512
  const int lg = (bid & 7) * 512 + (bid >> 3);      // XCD-grouping swizzle (bijective)
  const int bn = lg & 7;
  const int bm = lg >> 3;
  const int t = threadIdx.x;
  const int w = t >> 6, l = t & 63;
  const int wm = (w >> 1) * 64, wn = (w & 1) * 64;
  const int lrow = l & 15, lko = l >> 4;

  f32x4 zero4 = {0.f, 0.f, 0.f, 0.f};
  f32x4 acc[4][4];
  #pragma unroll
  for (int i = 0; i < 4; i++)
    #pragma unroll
    for (int j = 0; j < 4; j++) acc[i][j] = zero4;

  const int srow = t >> 2;          // 0..63
  const int scol = (t & 3) * 8;     // 0,8,16,24
  const u16* gA = A + (size_t)(bm * 128 + srow) * 1024 + scol;
  const u16* gB = B + (size_t)(bn * 128 + srow) * 1024 + scol;

  // prologue: stage tile 0 into buf 0
  #pragma unroll
  for (int i = 0; i < 2; i++) {
    __builtin_amdgcn_global_load_lds((gptr_t)(gA + (size_t)i * 64 * 1024),
                                     (lptr_t)&As[0][(i * 64 + srow) * 32 + scol], 16, 0, 0);
    __builtin_amdgcn_global_load_lds((gptr_t)(gB + (size_t)i * 64 * 1024),
                                     (lptr_t)&Bs[0][(i * 64 + srow) * 32 + scol], 16, 0, 0);
  }
  __syncthreads();  // drains vmcnt -> tile 0 ready & visible

  for (int kt = 0; kt < 32; ++kt) {
    const int cur = kt & 1;
    if (kt < 31) {                  // issue next-tile stage into the other buffer
      const int nk = (kt + 1) * 32;
      #pragma unroll
      for (int i = 0; i < 2; i++) {
        __builtin_amdgcn_global_load_lds((gptr_t)(gA + (size_t)i * 64 * 1024 + nk),
                                         (lptr_t)&As[cur ^ 1][(i * 64 + srow) * 32 + scol], 16, 0, 0);
        __builtin_amdgcn_global_load_lds((gptr_t)(gB + (size_t)i * 64 * 1024 + nk),
                                         (lptr_t)&Bs[cur ^ 1][(i * 64 + srow) * 32 + scol], 16, 0, 0);
      }
    }
    s16x8 a[4], b[4];
    #pragma unroll
    for (int mi = 0; mi < 4; mi++) a[mi] = *(const s16x8*)&As[cur][(wm + mi * 16 + lrow) * 32 + lko * 8];
    #pragma unroll
    for (int ni = 0; ni < 4; ni++) b[ni] = *(const s16x8*)&Bs[cur][(wn + ni * 16 + lrow) * 32 + lko * 8];
    #pragma unroll
    for (int mi = 0; mi < 4; mi++)
      #pragma unroll
      for (int ni = 0; ni < 4; ni++)
        acc[mi][ni] = __builtin_amdgcn_mfma_f32_16x16x32_bf16(a[mi], b[ni], acc[mi][ni], 0, 0, 0);
    __syncthreads();  // drain: next tile staged+visible; this tile's reads complete
  }
  const int rbase = (l >> 4) * 4;
  #pragma unroll
  for (int mi = 0; mi < 4; mi++)
    #pragma unroll
    for (int ni = 0; ni < 4; ni++) {
      int gcol = bn * 128 + wn + ni * 16 + lrow;
      if (gcol >= 1000) continue;
      #pragma unroll
      for (int j = 0; j < 4; j++) {
        int grow = bm * 128 + wm + mi * 16 + rbase + j;
        C[(size_t)grow * 1000 + gcol] = f2bf(acc[mi][ni][j]);
      }
    }
}

// ---------------- k2: screen + pipelined exact rescore + top-2; writes mixed (+probs if WPROBS)
__global__ __launch_bounds__(256) void k_wprobs(const int2* __restrict__ resc,
                                                const float2* __restrict__ resw,
                                                float* __restrict__ probs);

template<bool WPROBS>
__global__ __launch_bounds__(256) void k_topk(const float* __restrict__ feat,
                                              const float* __restrict__ prompts,
                                              const u16* __restrict__ sims,
                                              int2* __restrict__ resc,
                                              float2* __restrict__ resw,
                                              float* __restrict__ mixed,
                                              float* __restrict__ probs) {
  const int l = threadIdx.x & 63;
  const int row = blockIdx.x * 4 + (threadIdx.x >> 6);
  const u16* srow = sims + (size_t)row * 1000;
  const float NEG = -3.0e38f;
  // paired u32 sims load: slot jj holds col 2l + 128*(jj>>1) + (jj&1)
  float s[16];
  #pragma unroll
  for (int j = 0; j < 8; j++) {
    int c = 2 * l + 128 * j;
    if (c + 1 < 1000) {
      uint32_t v = *(const uint32_t*)(srow + c);
      s[2 * j] = bf2f((u16)(v & 0xFFFFu));
      s[2 * j + 1] = bf2f((u16)(v >> 16));
    } else {
      s[2 * j] = (c < 1000) ? bf2f(srow[c]) : NEG;
      s[2 * j + 1] = NEG;
    }
  }
  // per-lane top-2, wave butterfly
  float a1 = NEG, a2 = NEG;
  #pragma unroll
  for (int j = 0; j < 16; j++) {
    float v = s[j];
    bool g1 = v > a1;
    a2 = g1 ? a1 : fmaxf(a2, v);
    a1 = g1 ? v : a1;
  }
  #pragma unroll
  for (int off = 32; off; off >>= 1) {
    float b1 = __shfl_xor(a1, off), b2 = __shfl_xor(a2, off);
    float m1 = fmaxf(a1, b1);
    float m2 = fmaxf(fminf(a1, b1), fmaxf(a2, b2));
    a1 = m1; a2 = m2;
  }
  const float T = a2 - 0.25f;       // stored-scale margin (round-8 analysis)
  uint32_t mask = 0;
  #pragma unroll
  for (int j = 0; j < 16; j++) {
    int c = 2 * l + 128 * (j >> 1) + (j & 1);
    if (c < 1000 && s[j] >= T) mask |= (1u << j);
  }
  // survivor count (wave-uniform)
  int cnt = __popc(mask);
  #pragma unroll
  for (int off = 32; off; off >>= 1) cnt += __shfl_xor(cnt, off);
  // extract up to 8 survivor cols (static-indexed; lowest-lane, lowest-bit order)
  int scols[8];
  uint32_t m = mask;
  #pragma unroll
  for (int it = 0; it < 8; it++) {
    unsigned long long act = __ballot(m != 0);
    int ln = act ? (int)__ffsll(act) - 1 : 0;
    int fj = __ffs(m) - 1;
    int myc = 2 * l + 128 * ((fj >> 1) & 7) + (fj & 1);
    int bc = __shfl(myc, ln);
    scols[it] = (bc < 1000) ? bc : 999;
    if (act && l == ln) m &= (m - 1);
  }
  // feat row, norm
  const int base = l * 16;
  float q[16];
  const float4* fr = (const float4*)(feat + (size_t)row * 1024 + base);
  #pragma unroll
  for (int g = 0; g < 4; g++) {
    float4 x = fr[g];
    q[g * 4 + 0] = x.x; q[g * 4 + 1] = x.y; q[g * 4 + 2] = x.z; q[g * 4 + 3] = x.w;
  }
  float qq = 0.f;
  #pragma unroll
  for (int e = 0; e < 16; e++) qq += q[e] * q[e];
  #pragma unroll
  for (int off = 32; off; off >>= 1) qq += __shfl_xor(qq, off);
  float rn = 1.0f / fmaxf(sqrtf(qq), 1e-12f);
  // pipelined exact rescore over nact survivors (ping-pong prefetch, static indexing)
  const int nact = cnt < 8 ? cnt : 8;
  float s1 = NEG, s2 = NEG;
  int c1 = 0x40000000, c2 = 0x40000000;
  float4 bufA[4], bufB[4];
  {
    const float4* p0 = (const float4*)(prompts + (size_t)scols[0] * 1024 + base);
    #pragma unroll
    for (int g = 0; g < 4; g++) bufA[g] = p0[g];
  }
  #pragma unroll
  for (int it = 0; it < 8; it++) {
    if (it >= nact) break;          // wave-uniform
    if (it + 1 < nact) {            // prefetch next into the other buffer
      const int nidx = (it + 1 < 8) ? it + 1 : 7;
      const float4* pn = (const float4*)(prompts + (size_t)scols[nidx] * 1024 + base);
      if ((it & 1) == 0) {
        #pragma unroll
        for (int g = 0; g < 4; g++) bufB[g] = pn[g];
      } else {
        #pragma unroll
        for (int g = 0; g < 4; g++) bufA[g] = pn[g];
      }
    }
    float d = 0.f, nn = 0.f;
    if ((it & 1) == 0) {
      #pragma unroll
      for (int g = 0; g < 4; g++) {
        float4 x = bufA[g];
        d += q[g * 4 + 0] * x.x; d += q[g * 4 + 1] * x.y;
        d += q[g * 4 + 2] * x.z; d += q[g * 4 + 3] * x.w;
        nn += x.x * x.x + x.y * x.y + x.z * x.z + x.w * x.w;
      }
    } else {
      #pragma unroll
      for (int g = 0; g < 4; g++) {
        float4 x = bufB[g];
        d += q[g * 4 + 0] * x.x; d += q[g * 4 + 1] * x.y;
        d += q[g * 4 + 2] * x.z; d += q[g * 4 + 3] * x.w;
        nn += x.x * x.x + x.y * x.y + x.z * x.z + x.w * x.w;
      }
    }
    #pragma unroll
    for (int off = 32; off; off >>= 1) {
      d += __shfl_xor(d, off);
      nn += __shfl_xor(nn, off);
    }
    float sc = d * rn / fmaxf(sqrtf(nn), 1e-12f);
    int bc = scols[it];
    bool b1w = (sc > s1) || (sc == s1 && bc < c1);
    bool b2w = (sc > s2) || (sc == s2 && bc < c2);
    if (b1w) { s2 = s1; c2 = c1; s1 = sc; c1 = bc; }
    else if (b2w) { s2 = sc; c2 = bc; }
  }
  // rare tail: cnt > 8 — serial loop over remaining bits
  if (cnt > 8) {
    while (true) {
      unsigned long long act = __ballot(m != 0);
      if (!act) break;
      int ln = (int)__ffsll(act) - 1;
      int fj = __ffs(m) - 1;
      int myc = 2 * l + 128 * ((fj >> 1) & 7) + (fj & 1);
      int bc = __shfl(myc, ln);
      if (l == ln) m &= (m - 1);
      bc = (bc < 1000) ? bc : 999;
      const float4* pr = (const float4*)(prompts + (size_t)bc * 1024 + base);
      float d = 0.f, nn = 0.f;
      #pragma unroll
      for (int g = 0; g < 4; g++) {
        float4 x = pr[g];
        d += q[g * 4 + 0] * x.x; d += q[g * 4 + 1] * x.y;
        d += q[g * 4 + 2] * x.z; d += q[g * 4 + 3] * x.w;
        nn += x.x * x.x + x.y * x.y + x.z * x.z + x.w * x.w;
      }
      #pragma unroll
      for (int off = 32; off; off >>= 1) {
        d += __shfl_xor(d, off);
        nn += __shfl_xor(nn, off);
      }
      float sc = d * rn / fmaxf(sqrtf(nn), 1e-12f);
      bool b1w = (sc > s1) || (sc == s1 && bc < c1);
      bool b2w = (sc > s2) || (sc == s2 && bc < c2);
      if (b1w) { s2 = s1; c2 = c1; s1 = sc; c1 = bc; }
      else if (b2w) { s2 = sc; c2 = bc; }
    }
  }
  float e = expf(fminf(s2 - s1, 0.0f) * (1.0f / 0.07f));  // (0,1]
  float w1 = 1.0f / (1.0f + e);
  float w2 = e / (1.0f + e);
  if (l == 0) {
    resc[row] = make_int2(c1, c2);
    resw[row] = make_float2(w1, w2);
  }
  // mixed = w1*P1 + w2*P2 (mixed region holds only dead feat_bf scratch -> safe)
  const float4* P1 = (const float4*)(prompts + (size_t)c1 * 1024 + base);
  const float4* P2 = (const float4*)(prompts + (size_t)c2 * 1024 + base);
  float* mrow = mixed + (size_t)row * 1024 + base;
  #pragma unroll
  for (int g = 0; g < 4; g++) {
    float4 x = P1[g], y = P2[g];
    float4 o;
    o.x = w1 * x.x + w2 * y.x;
    o.y = w1 * x.y + w2 * y.y;
    o.z = w1 * x.z + w2 * y.z;
    o.w = w1 * x.w + w2 * y.w;
    ((float4*)mrow)[g] = o;
  }
  if (WPROBS) {  // only when sims lives in ws (probs region clean)
    float* prow = probs + (size_t)row * 1000;
    #pragma unroll
    for (int j = 0; j < 16; j++) {
      int c = l + 64 * j;
      if (c < 1000) prow[c] = (c == c1) ? w1 : ((c == c2) ? w2 : 0.0f);
    }
  }
}

// ---------------- k3 (fallback only): write probs region (overwrites dead sims scratch)
__global__ __launch_bounds__(256) void k_wprobs(const int2* __restrict__ resc,
                                                const float2* __restrict__ resw,
                                                float* __restrict__ probs) {
  const int row = blockIdx.x;
  const int t = threadIdx.x;
  if (t >= 250) return;
  int2 cc = resc[row];
  float2 ww = resw[row];
  const int base = t * 4;
  float4 z;
  z.x = (base + 0 == cc.x) ? ww.x : ((base + 0 == cc.y) ? ww.y : 0.0f);
  z.y = (base + 1 == cc.x) ? ww.x : ((base + 1 == cc.y) ? ww.y : 0.0f);
  z.z = (base + 2 == cc.x) ? ww.x : ((base + 2 == cc.y) ? ww.y : 0.0f);
  z.w = (base + 3 == cc.x) ? ww.x : ((base + 3 == cc.y) ? ww.y : 0.0f);
  ((float4*)(probs + (size_t)row * 1000))[t] = z;
}

extern "C" void kernel_launch(void* const* d_in, const int* in_sizes, int n_in,
                              void* d_out, int out_size, void* d_ws, size_t ws_size,
                              hipStream_t stream) {
  int fi = 0, pi = 1;
  for (int i = 0; i < n_in; i++) {
    if (in_sizes[i] == 67108864) fi = i;
    else if (in_sizes[i] == 1024000) pi = i;
  }
  const float* feat = (const float*)d_in[fi];
  const float* prompts = (const float*)d_in[pi];

  float* mixed = (float*)d_out;                 // [65536*1024] f32 (output 0)
  float* probs = mixed + 67108864ull;           // [65536*1000] f32 (output 1)

  // ws: [0,2MB) p_bf; [2,2.5MB) resc; [2.5,3MB) resw; [3MB,128MB) sims (big-ws path)
  u16* p_bf = (u16*)d_ws;
  int2* resc = (int2*)((char*)d_ws + (2ull << 20));
  float2* resw = (float2*)((char*)d_ws + (2ull << 20) + (512ull << 10));

  // scratch: feat_bf at start of MIXED region (dead before k_topk writes mixed).
  // sims: in ws if it fits (needs exactly 128 MiB total), else start of PROBS region.
  u16* feat_bf = (u16*)mixed;
  const bool big_ws = ws_size >= (1ull << 27);
  u16* sims = big_ws ? (u16*)((char*)d_ws + (3ull << 20)) : (u16*)probs;

  hipLaunchKernelGGL(k_prep_prompts, dim3(1024), dim3(256), 0, stream, prompts, p_bf);
  hipLaunchKernelGGL(k_feat, dim3(2048), dim3(256), 0, stream, feat, feat_bf);
  hipLaunchKernelGGL(k_sims, dim3(4096), dim3(256), 0, stream, feat_bf, p_bf, sims);
  if (big_ws) {
    hipLaunchKernelGGL((k_topk<true>), dim3(16384), dim3(256), 0, stream,
                       feat, prompts, sims, resc, resw, mixed, probs);
  } else {
    hipLaunchKernelGGL((k_topk<false>), dim3(16384), dim3(256), 0, stream,
                       feat, prompts, sims, resc, resw, mixed, probs);
    hipLaunchKernelGGL(k_wprobs, dim3(65536), dim3(256), 0, stream, resc, resw, probs);
  }
}